// Round 7
// baseline (630.085 us; speedup 1.0000x reference)
//
#include <hip/hip_runtime.h>
#include <math.h>

#define BATCH 8
#define CIN 512
#define COUT 256
#define HH 64
#define WW 64
#define WDIM 512

typedef __attribute__((ext_vector_type(8))) short bf16x8;
typedef __attribute__((ext_vector_type(16))) float f32x16;
typedef __attribute__((ext_vector_type(2))) float f32x2;
typedef __attribute__((ext_vector_type(4))) float f32x4;

__device__ __forceinline__ unsigned short f2bf(float f) {
    union { float f; unsigned u; } v; v.f = f;
    unsigned r = v.u + 0x7FFFu + ((v.u >> 16) & 1u);
    return (unsigned short)(r >> 16);
}

// ---------------------------------------------------------------------------
// PREP kernel: fuses transpose (blocks 0..511) + style_mod (blocks 512..1535).
// (unchanged from round 6)
// ---------------------------------------------------------------------------
__global__ __launch_bounds__(256)
void prep_kernel(const float* __restrict__ input,
                 const float* __restrict__ style,
                 const float* __restrict__ mod_weight,
                 const float* __restrict__ mod_bias,
                 unsigned short* __restrict__ in_t,
                 float* __restrict__ s,
                 uint4* __restrict__ zp) {
    int L = blockIdx.x;
    int t = threadIdx.x;
    __shared__ unsigned short tile[64 * 512];
    if (L < 512) {
        int b = L >> 6, y = L & 63;
        int xq = t & 15, cw = t >> 4;
        const float* src = input + ((size_t)b * CIN * 64 + y) * 64;
        for (int it = 0; it < 32; ++it) {
            int ci = it * 16 + cw;
            float4 v4 = *(const float4*)(src + (size_t)ci * 4096 + xq * 4);
            float vv[4] = {v4.x, v4.y, v4.z, v4.w};
#pragma unroll
            for (int i = 0; i < 4; ++i) {
                int x = xq * 4 + i;
                tile[x * 512 + ((((ci >> 3) ^ (x & 7)) << 3) | (ci & 7))] = f2bf(vv[i]);
            }
        }
        __syncthreads();
        int wv = t >> 6, lane = t & 63;
        unsigned short* dst = in_t + (((size_t)b * 64 + y) * 64) * 512;
        for (int it = 0; it < 16; ++it) {
            int xx = it * 4 + wv;
            uint4 v = *(const uint4*)&tile[xx * 512 + ((lane ^ (xx & 7)) << 3)];
            *(uint4*)(dst + (size_t)xx * 512 + lane * 8) = v;
        }
    } else {
        if (L == 512 && t < 64) zp[t] = make_uint4(0u, 0u, 0u, 0u);
        int q = (L - 512) * 4 + (t >> 6);
        int b = q >> 9, ci = q & 511;
        int lane = t & 63;
        const float* mw = mod_weight + (size_t)ci * WDIM;
        const float* st = style + (size_t)b * WDIM;
        float acc = 0.f;
        for (int d = lane; d < WDIM; d += 64) acc += mw[d] * st[d];
        for (int off = 32; off > 0; off >>= 1) acc += __shfl_down(acc, off);
        if (lane == 0) s[q] = acc * 0.04419417382415922f + mod_bias[ci];
    }
}

// ---------------------------------------------------------------------------
// demod[b,co] = rsqrt(sum((scale*w*s)^2)+1e-8)  (restored: fold blocks no
// longer span all ci so demod must be computed separately)
// ---------------------------------------------------------------------------
__global__ __launch_bounds__(256)
void demod_kernel(const float* __restrict__ weight,
                  const float* __restrict__ s,
                  float* __restrict__ demod) {
    int b = blockIdx.x / COUT, co = blockIdx.x % COUT;
    int t = threadIdx.x;
    const float scale = 0.014731391274719739f;
    const float* wco = weight + (size_t)co * CIN * 9;
    const float* sb = s + (size_t)b * CIN;
    float acc = 0.f;
    for (int i = t; i < CIN * 9; i += 256) {
        int ci = i / 9;
        float v = scale * wco[i] * sb[ci];
        acc += v * v;
    }
    __shared__ float red[256];
    red[t] = acc;
    __syncthreads();
    if (t < 128) red[t] += red[t + 128];
    __syncthreads();
    if (t < 64) {
        float v = red[t] + red[t + 64];
        for (int off = 32; off > 0; off >>= 1) v += __shfl_down(v, off);
        if (t == 0) demod[blockIdx.x] = rsqrtf(v + 1e-8f);
    }
}

// ---------------------------------------------------------------------------
// FOLD kernel -> TRANSPOSED layout for conv's direct-to-register B loads:
// W4t[b][py][c=ci0/16][tap][px][h][co] : 16B frag = 8 consecutive ci (bf16)
// frag byte addr = (((((b*2+py)*32+c)*9+tap)*2+px)*2+h)*4096 + co*16
// Block = (b, c, h) [512 blocks], thread = co. Stores: stride-16B across
// threads -> perfectly coalesced 4KB per wave-instruction.
// ---------------------------------------------------------------------------
__global__ __launch_bounds__(256)
void fold_kernel(const float* __restrict__ weight,
                 const float* __restrict__ s,
                 const float* __restrict__ dm,
                 unsigned short* __restrict__ W4t) {
    int bc = blockIdx.x;                 // 8 b * 32 c * 2 h = 512
    int b = bc >> 6, c = (bc >> 1) & 31, h = bc & 1;
    int co = threadIdx.x;
    const float scale = 0.014731391274719739f;
    float dmv = dm[b * COUT + co] * scale;
    int ci0 = c * 16 + h * 8;

    float wm[8][9];
#pragma unroll
    for (int j = 0; j < 8; ++j) {
        float m = s[b * CIN + ci0 + j] * dmv;
        const float* wp = weight + ((size_t)co * CIN + ci0 + j) * 9;
#pragma unroll
        for (int k = 0; k < 9; ++k) wm[j][k] = wp[k] * m;
    }

    const float T[2][3][3] = {
        {{0.f, .25f, .75f}, {.75f, .75f, .25f}, {.25f, 0.f, 0.f}},
        {{0.f, 0.f, .25f}, {.25f, .75f, .75f}, {.75f, .25f, 0.f}}};

#pragma unroll
    for (int py = 0; py < 2; ++py)
#pragma unroll
        for (int dy = 0; dy < 3; ++dy)
#pragma unroll
            for (int dx = 0; dx < 3; ++dx)
#pragma unroll
                for (int px = 0; px < 2; ++px) {
                    unsigned int pk[4];
#pragma unroll
                    for (int jp = 0; jp < 4; ++jp) {
                        unsigned short lo, hi;
#pragma unroll
                        for (int half = 0; half < 2; ++half) {
                            int j = jp * 2 + half;
                            float acc = 0.f;
#pragma unroll
                            for (int ky = 0; ky < 3; ++ky)
#pragma unroll
                                for (int kx = 0; kx < 3; ++kx)
                                    acc += T[py][dy][ky] * T[px][dx][kx] * wm[j][ky * 3 + kx];
                            if (half == 0) lo = f2bf(acc); else hi = f2bf(acc);
                        }
                        pk[jp] = (unsigned int)lo | ((unsigned int)hi << 16);
                    }
                    size_t frag = (((((size_t)(b * 2 + py) * 32 + c) * 9 + (dy * 3 + dx)) * 2 + px) * 2 + h) * 256 + co;
                    uint4 v; v.x = pk[0]; v.y = pk[1]; v.z = pk[2]; v.w = pk[3];
                    *(uint4*)(W4t + frag * 8) = v;
                }
}

// ---------------------------------------------------------------------------
// Kernel 5: MFMA conv, 512 threads / 8 waves. wave w = output row r (8 rows).
// NEW: only A (input) is LDS-staged (3-issue DMA double-buffer). B (weights)
// load straight from global -> registers, coalesced via W4t layout; per-tap
// working set 4KB is L1-resident so the 8-wave redundancy is L1-served.
// LDS reads drop 432 -> 144 per chunk per CU: the additive LDS+MFMA floor
// (rounds 0-6's 41% plateau) moves from ~9.8K to ~6.4K cyc/chunk, and B
// traffic shifts to the VMEM pipe where the compiler software-pipelines it.
//
// A slot order (conflict-free): slot = (row*2+h)*66 + cell ; tasks 0..1319,
// pad to 1536 (3 issues/thread, dummy -> zeropage, 32B/chunk advance ok).
// ---------------------------------------------------------------------------
#define ABUF 24576                     // 1536 slots * 16B
#define LDS_TOTAL2 73728               // max(2*ABUF, epilogue 8*9216)

__global__ __launch_bounds__(512, 2)
void conv_kernel(const unsigned short* __restrict__ in_t,
                 const unsigned short* __restrict__ W4t,
                 const uint4* __restrict__ zeropage,
                 float* __restrict__ out) {
    __shared__ char lds[LDS_TOTAL2];
    int L = blockIdx.x;                 // 512 blocks
    int g = ((L >> 6) << 3) | (L & 7);  // XCD swizzle
    int sbq = (L >> 3) & 7;
    int b = g >> 3, rgrp = g & 7;
    int py = rgrp >> 2, cb = rgrp & 3;
    int Y0 = sbq * 8;
    int t = threadIdx.x, w = t >> 6, lane = t & 63;
    int l31 = lane & 31, hf = lane >> 5;
    int r = w;

    const unsigned short* inb = in_t + (size_t)b * 64 * 64 * 512;

    // ---- A staging pointers: 3 per thread ----
    const char* gp[3];
#pragma unroll
    for (int k = 0; k < 3; ++k) {
        int task = t + (k << 9);
        const void* p;
        if (task < 1320) {
            int row = task / 132;
            int rem = task - row * 132;
            int h = rem / 66;
            int cell = rem - h * 66;
            int y = Y0 - 1 + row, x = cell - 1;
            p = ((unsigned)y < 64u && (unsigned)x < 64u)
                    ? (const void*)(inb + ((size_t)(y * 64 + x) * 512 + h * 8))
                    : (const void*)zeropage;
        } else {
            p = (const void*)zeropage;
        }
        gp[k] = (const char*)p;
    }

    // ---- B base pointer (per-lane, coalesced 16B loads) ----
    // byte = (b*2+py)*4718592 + cc*147456 + (tap*2+px)*8192 + hf*4096
    //        + (cb*64 + nt*32 + l31)*16
    const char* wB = (const char*)W4t + (size_t)(b * 2 + py) * 4718592 +
                     (size_t)(cb * 1024 + hf * 4096 + l31 * 16);

    f32x16 acc[2][2][2];                // [px][mt][nt]
#pragma unroll
    for (int px = 0; px < 2; ++px)
#pragma unroll
        for (int mt = 0; mt < 2; ++mt)
#pragma unroll
            for (int nt = 0; nt < 2; ++nt) acc[px][mt][nt] = (f32x16)0.f;

#define STAGE(BUFOFF)                                                             \
    {                                                                             \
        char* lb = lds + (BUFOFF) + (w << 10);                                    \
        _Pragma("unroll")                                                         \
        for (int k = 0; k < 3; ++k) {                                             \
            __builtin_amdgcn_global_load_lds(                                     \
                (const __attribute__((address_space(1))) void*)gp[k],             \
                (__attribute__((address_space(3))) void*)(lb + (k << 13)),        \
                16, 0, 0);                                                        \
            gp[k] += 32;                                                          \
        }                                                                         \
    }

#define BAR()                                  \
    {                                          \
        asm volatile("" ::: "memory");         \
        __builtin_amdgcn_s_barrier();          \
        asm volatile("" ::: "memory");         \
    }

    // 2-deep tap pipeline: A from LDS, B from global (compiler-pipelined).
#define COMPUTE(BUFOFF, WC)                                                         \
    {                                                                               \
        const char* Bp = lds + (BUFOFF);                                            \
        const char* Wc = (WC);                                                      \
        bf16x8 Ra0[2], Ra1[2], Rb[2][2][2];                                         \
        {   /* prologue: tap 0 -> parity 0 */                                       \
            int cell0 = ((1 + r - 1) * 2 + hf) * 66 + (1 + l31 - 1);                \
            Ra0[0] = *(const bf16x8*)(Bp + (cell0 << 4));                           \
            Ra1[0] = *(const bf16x8*)(Bp + ((cell0 + 32) << 4));                    \
            _Pragma("unroll")                                                       \
            for (int px = 0; px < 2; ++px)                                          \
                _Pragma("unroll")                                                   \
                for (int nt = 0; nt < 2; ++nt)                                      \
                    Rb[0][px][nt] = *(const bf16x8*)(Wc + (px << 13) + (nt << 9));  \
        }                                                                           \
        _Pragma("unroll")                                                           \
        for (int tap = 0; tap < 9; ++tap) {                                         \
            const int cur = tap & 1, nxt = cur ^ 1;                                 \
            if (tap < 8) {                                                          \
                const int tn = tap + 1;                                             \
                const int dy = tn / 3 - 1, dx = tn % 3 - 1;                         \
                int cell0 = ((1 + r + dy) * 2 + hf) * 66 + (1 + l31 + dx);          \
                Ra0[nxt] = *(const bf16x8*)(Bp + (cell0 << 4));                     \
                Ra1[nxt] = *(const bf16x8*)(Bp + ((cell0 + 32) << 4));              \
                _Pragma("unroll")                                                   \
                for (int px = 0; px < 2; ++px)                                      \
                    _Pragma("unroll")                                               \
                    for (int nt = 0; nt < 2; ++nt)                                  \
                        Rb[nxt][px][nt] = *(const bf16x8*)(Wc +                     \
                            (((tn * 2 + px) << 13) + (nt << 9)));                   \
            }                                                                       \
            _Pragma("unroll")                                                       \
            for (int px = 0; px < 2; ++px) {                                        \
                acc[px][0][0] = __builtin_amdgcn_mfma_f32_32x32x16_bf16(            \
                    Ra0[cur], Rb[cur][px][0], acc[px][0][0], 0, 0, 0);              \
                acc[px][0][1] = __builtin_amdgcn_mfma_f32_32x32x16_bf16(            \
                    Ra0[cur], Rb[cur][px][1], acc[px][0][1], 0, 0, 0);              \
                acc[px][1][0] = __builtin_amdgcn_mfma_f32_32x32x16_bf16(            \
                    Ra1[cur], Rb[cur][px][0], acc[px][1][0], 0, 0, 0);              \
                acc[px][1][1] = __builtin_amdgcn_mfma_f32_32x32x16_bf16(            \
                    Ra1[cur], Rb[cur][px][1], acc[px][1][1], 0, 0, 0);              \
            }                                                                       \
        }                                                                           \
    }

    STAGE(0);                                   // chunk 0 A -> buf0
    asm volatile("s_waitcnt vmcnt(0)" ::: "memory");
    BAR();
#pragma unroll 1
    for (int cc = 0; cc < 32; ++cc) {
        if (cc < 31) STAGE(((cc + 1) & 1) * ABUF);   // next chunk's A, issued early
        asm volatile("" ::: "memory");
        __builtin_amdgcn_s_setprio(1);
        COMPUTE((cc & 1) * ABUF, wB + (size_t)cc * 147456);
        __builtin_amdgcn_s_setprio(0);
        asm volatile("s_waitcnt vmcnt(0)" ::: "memory");  // A(cc+1) landed (full
        BAR();                                            // compute to cover it)
    }
    __syncthreads();    // before epilogue overlays the A buffers

    // ---- epilogue: per-wave LDS transpose to (co, fx), coalesced stores ----
    float* ob = (float*)(lds + w * 9216);   // [64 co][36 floats pitch]
    int fy = 2 * (Y0 + r) + py;
    float* outb = out + (((size_t)b * COUT + cb * 64) * 128 + fy) * 128;
#pragma unroll
    for (int mt = 0; mt < 2; ++mt)
#pragma unroll
        for (int hh = 0; hh < 2; ++hh) {
            int fx0 = mt * 64 + hh * 32;
#pragma unroll
            for (int nt = 0; nt < 2; ++nt)
#pragma unroll
                for (int j = 0; j < 8; ++j) {
                    int reg = hh * 8 + j;
                    int Xl = (j & 3) + ((j >> 2) << 3) + (hf << 2);
                    int cw = nt * 32 + l31;
                    f32x2 v;
                    v.x = acc[0][mt][nt][reg];
                    v.y = acc[1][mt][nt][reg];
                    *(f32x2*)(ob + cw * 36 + Xl * 2) = v;
                }
            asm volatile("s_waitcnt lgkmcnt(0)" ::: "memory");
#pragma unroll
            for (int rr = 0; rr < 2; ++rr) {
                int co_r = (lane >> 1) + rr * 32;
                const float* srcp = ob + co_r * 36 + (lane & 1) * 16;
                float* dstp = outb + (size_t)co_r * 16384 + fx0 + (lane & 1) * 16;
#pragma unroll
                for (int q = 0; q < 4; ++q)
                    *(f32x4*)(dstp + q * 4) = *(const f32x4*)(srcp + q * 4);
            }
            asm volatile("s_waitcnt lgkmcnt(0)" ::: "memory");
        }
#undef STAGE
#undef BAR
#undef COMPUTE
}

// ---------------------------------------------------------------------------
// FALLBACK path kernels (only used if ws_size too small for MFMA pipeline)
// ---------------------------------------------------------------------------
__global__ __launch_bounds__(64)
void style_mod_kernel(const float* __restrict__ style,
                      const float* __restrict__ mod_weight,
                      const float* __restrict__ mod_bias,
                      float* __restrict__ s) {
    int idx = blockIdx.x;
    int b = idx / CIN, ci = idx % CIN;
    int lane = threadIdx.x;
    const float* mw = mod_weight + (size_t)ci * WDIM;
    const float* st = style + (size_t)b * WDIM;
    float acc = 0.f;
    for (int d = lane; d < WDIM; d += 64) acc += mw[d] * st[d];
    for (int off = 32; off > 0; off >>= 1) acc += __shfl_down(acc, off);
    if (lane == 0) s[idx] = acc * 0.04419417382415922f + mod_bias[ci];
}

__global__ __launch_bounds__(256)
void fused_upconv_blur_kernel(const float* __restrict__ input,
                              const float* __restrict__ weight,
                              const float* __restrict__ s,
                              const float* __restrict__ demod,
                              float* __restrict__ out) {
    const int t = threadIdx.x;
    const int tY = blockIdx.x >> 2, tX = blockIdx.x & 3;
    const int cob = blockIdx.y * 4;
    const int b = blockIdx.z;
    const int Y0 = tY * 16, X0 = tX * 16;
    __shared__ __attribute__((aligned(16))) float patch[19][20];
    __shared__ __attribute__((aligned(16))) float wsm[4][12];
    __shared__ __attribute__((aligned(16))) float out1[36][37];
    __shared__ __attribute__((aligned(16))) float tmpb[35][33];
    const float scale = 0.014731391274719739f;
    float dmv[4];
#pragma unroll
    for (int c = 0; c < 4; ++c) dmv[c] = demod[b * COUT + cob + c] * scale;
    float a0[4][4], a1[4][4];
#pragma unroll
    for (int c = 0; c < 4; ++c)
#pragma unroll
        for (int q = 0; q < 4; ++q) { a0[c][q] = 0.f; a1[c][q] = 0.f; }
    const int p0 = t, p1 = t + 256;
    const int qY0 = p0 / 18, qX0 = p0 % 18;
    const int qY1s = p1 / 18, qX1 = p1 % 18;
    const bool act1 = (p1 < 324);
    const int qY1 = act1 ? qY1s : 0;
    const float* inb = input + (size_t)b * CIN * HH * WW;
    const float* sb = s + (size_t)b * CIN;
    for (int ci = 0; ci < CIN; ++ci) {
        const float* inc = inb + (size_t)ci * (HH * WW);
        for (int idx = t; idx < 361; idx += 256) {
            int rr = idx / 19, cc = idx - rr * 19;
            int gr = Y0 - 2 + rr, gc = X0 - 2 + cc;
            float v = 0.f;
            if ((unsigned)gr < 64u && (unsigned)gc < 64u) v = inc[gr * 64 + gc];
            patch[rr][cc] = v;
        }
        if (t < 36) {
            int c = t / 9, k = t - c * 9;
            wsm[c][k] = weight[((size_t)(cob + c) * CIN + ci) * 9 + k] * sb[ci] * dmv[c];
        }
        __syncthreads();
        const float i00a = patch[qY0][qX0], i01a = patch[qY0][qX0 + 1];
        const float i10a = patch[qY0 + 1][qX0], i11a = patch[qY0 + 1][qX0 + 1];
        float i00b = 0.f, i01b = 0.f, i10b = 0.f, i11b = 0.f;
        if (act1) {
            i00b = patch[qY1][qX1]; i01b = patch[qY1][qX1 + 1];
            i10b = patch[qY1 + 1][qX1]; i11b = patch[qY1 + 1][qX1 + 1];
        }
#pragma unroll
        for (int c = 0; c < 4; ++c) {
            const float4 wA = *(const float4*)&wsm[c][0];
            const float4 wB = *(const float4*)&wsm[c][4];
            const float w8v = wsm[c][8];
            a0[c][0] += i11a * wA.x + i10a * wA.z + i01a * wB.z + i00a * w8v;
            a0[c][1] += i11a * wA.y + i01a * wB.w;
            a0[c][2] += i11a * wA.w + i10a * wB.y;
            a0[c][3] += i11a * wB.x;
            if (act1) {
                a1[c][0] += i11b * wA.x + i10b * wA.z + i01b * wB.z + i00b * w8v;
                a1[c][1] += i11b * wA.y + i01b * wB.w;
                a1[c][2] += i11b * wA.w + i10b * wB.y;
                a1[c][3] += i11b * wB.x;
            }
        }
        __syncthreads();
    }
    const size_t out_base = ((size_t)b * COUT + cob) * 128 * 128;
    for (int c = 0; c < 4; ++c) {
        __syncthreads();
        out1[2 * qY0][2 * qX0] = a0[c][0];
        out1[2 * qY0][2 * qX0 + 1] = a0[c][1];
        out1[2 * qY0 + 1][2 * qX0] = a0[c][2];
        out1[2 * qY0 + 1][2 * qX0 + 1] = a0[c][3];
        if (act1) {
            out1[2 * qY1][2 * qX1] = a1[c][0];
            out1[2 * qY1][2 * qX1 + 1] = a1[c][1];
            out1[2 * qY1 + 1][2 * qX1] = a1[c][2];
            out1[2 * qY1 + 1][2 * qX1 + 1] = a1[c][3];
        }
        __syncthreads();
        for (int idx = t; idx < 35 * 32; idx += 256) {
            int rr = idx >> 5, x = idx & 31;
            tmpb[rr][x] = 0.25f * (out1[rr + 1][x + 1] + out1[rr + 1][x + 4])
                        + 0.75f * (out1[rr + 1][x + 2] + out1[rr + 1][x + 3]);
        }
        __syncthreads();
        float* outc = out + out_base + (size_t)c * 128 * 128;
        for (int idx = t; idx < 1024; idx += 256) {
            int oy = idx >> 5, x = idx & 31;
            float v = 0.25f * (tmpb[oy][x] + tmpb[oy + 3][x])
                    + 0.75f * (tmpb[oy + 1][x] + tmpb[oy + 2][x]);
            outc[(size_t)(2 * Y0 + oy) * 128 + (2 * X0 + x)] = v;
        }
    }
}

// ---------------------------------------------------------------------------
extern "C" void kernel_launch(void* const* d_in, const int* in_sizes, int n_in,
                              void* d_out, int out_size, void* d_ws, size_t ws_size,
                              hipStream_t stream) {
    const float* input      = (const float*)d_in[0];
    const float* style      = (const float*)d_in[1];
    const float* weight     = (const float*)d_in[2];
    const float* mod_weight = (const float*)d_in[3];
    const float* mod_bias   = (const float*)d_in[4];
    float* out = (float*)d_out;

    // ws layout: s(16KB) | dm(8KB) | zeropage(1KB)+pad | in_t bf16 | W4t bf16
    const size_t OFF_S = 0, OFF_DM = 16384, OFF_ZP = 24576, OFF_INT = 32768;
    const size_t OFF_W4 = OFF_INT + (size_t)BATCH * 64 * 64 * CIN * 2;      // 33587200
    const size_t WS_NEEDED = OFF_W4 + (size_t)BATCH * 4 * 9 * COUT * CIN * 2; // 109084672

    float* s_buf  = (float*)((char*)d_ws + OFF_S);
    float* dm_buf = (float*)((char*)d_ws + OFF_DM);
    uint4* zp     = (uint4*)((char*)d_ws + OFF_ZP);

    if (ws_size >= WS_NEEDED) {
        unsigned short* in_t = (unsigned short*)((char*)d_ws + OFF_INT);
        unsigned short* W4t  = (unsigned short*)((char*)d_ws + OFF_W4);
        prep_kernel<<<1536, 256, 0, stream>>>(input, style, mod_weight, mod_bias,
                                              in_t, s_buf, zp);
        demod_kernel<<<BATCH * COUT, 256, 0, stream>>>(weight, s_buf, dm_buf);
        fold_kernel<<<BATCH * 32 * 2, 256, 0, stream>>>(weight, s_buf, dm_buf, W4t);
        conv_kernel<<<512, 512, 0, stream>>>(in_t, W4t, zp, out);
    } else {
        style_mod_kernel<<<BATCH * CIN, 64, 0, stream>>>(style, mod_weight, mod_bias, s_buf);
        demod_kernel<<<BATCH * COUT, 256, 0, stream>>>(weight, s_buf, dm_buf);
        fused_upconv_blur_kernel<<<dim3(16, COUT / 4, BATCH), 256, 0, stream>>>(
            input, weight, s_buf, dm_buf, out);
    }
}

// Round 8
// 378.280 us; speedup vs baseline: 1.6657x; 1.6657x over previous
//
#include <hip/hip_runtime.h>
#include <math.h>

#define BATCH 8
#define CIN 512
#define COUT 256
#define HH 64
#define WW 64
#define WDIM 512

typedef __attribute__((ext_vector_type(8))) short bf16x8;
typedef __attribute__((ext_vector_type(16))) float f32x16;
typedef __attribute__((ext_vector_type(2))) float f32x2;
typedef __attribute__((ext_vector_type(4))) float f32x4;

__device__ __forceinline__ unsigned short f2bf(float f) {
    union { float f; unsigned u; } v; v.f = f;
    unsigned r = v.u + 0x7FFFu + ((v.u >> 16) & 1u);
    return (unsigned short)(r >> 16);
}

// ---------------------------------------------------------------------------
// PREP kernel: fuses transpose (blocks 0..511) + style_mod (blocks 512..1535).
// (unchanged from round 6)
// ---------------------------------------------------------------------------
__global__ __launch_bounds__(256)
void prep_kernel(const float* __restrict__ input,
                 const float* __restrict__ style,
                 const float* __restrict__ mod_weight,
                 const float* __restrict__ mod_bias,
                 unsigned short* __restrict__ in_t,
                 float* __restrict__ s,
                 uint4* __restrict__ zp) {
    int L = blockIdx.x;
    int t = threadIdx.x;
    __shared__ unsigned short tile[64 * 512];
    if (L < 512) {
        int b = L >> 6, y = L & 63;
        int xq = t & 15, cw = t >> 4;
        const float* src = input + ((size_t)b * CIN * 64 + y) * 64;
        for (int it = 0; it < 32; ++it) {
            int ci = it * 16 + cw;
            float4 v4 = *(const float4*)(src + (size_t)ci * 4096 + xq * 4);
            float vv[4] = {v4.x, v4.y, v4.z, v4.w};
#pragma unroll
            for (int i = 0; i < 4; ++i) {
                int x = xq * 4 + i;
                tile[x * 512 + ((((ci >> 3) ^ (x & 7)) << 3) | (ci & 7))] = f2bf(vv[i]);
            }
        }
        __syncthreads();
        int wv = t >> 6, lane = t & 63;
        unsigned short* dst = in_t + (((size_t)b * 64 + y) * 64) * 512;
        for (int it = 0; it < 16; ++it) {
            int xx = it * 4 + wv;
            uint4 v = *(const uint4*)&tile[xx * 512 + ((lane ^ (xx & 7)) << 3)];
            *(uint4*)(dst + (size_t)xx * 512 + lane * 8) = v;
        }
    } else {
        if (L == 512 && t < 64) zp[t] = make_uint4(0u, 0u, 0u, 0u);
        int q = (L - 512) * 4 + (t >> 6);
        int b = q >> 9, ci = q & 511;
        int lane = t & 63;
        const float* mw = mod_weight + (size_t)ci * WDIM;
        const float* st = style + (size_t)b * WDIM;
        float acc = 0.f;
        for (int d = lane; d < WDIM; d += 64) acc += mw[d] * st[d];
        for (int off = 32; off > 0; off >>= 1) acc += __shfl_down(acc, off);
        if (lane == 0) s[q] = acc * 0.04419417382415922f + mod_bias[ci];
    }
}

// ---------------------------------------------------------------------------
// demod[b,co] = rsqrt(sum((scale*w*s)^2)+1e-8)
// ---------------------------------------------------------------------------
__global__ __launch_bounds__(256)
void demod_kernel(const float* __restrict__ weight,
                  const float* __restrict__ s,
                  float* __restrict__ demod) {
    int b = blockIdx.x / COUT, co = blockIdx.x % COUT;
    int t = threadIdx.x;
    const float scale = 0.014731391274719739f;
    const float* wco = weight + (size_t)co * CIN * 9;
    const float* sb = s + (size_t)b * CIN;
    float acc = 0.f;
    for (int i = t; i < CIN * 9; i += 256) {
        int ci = i / 9;
        float v = scale * wco[i] * sb[ci];
        acc += v * v;
    }
    __shared__ float red[256];
    red[t] = acc;
    __syncthreads();
    if (t < 128) red[t] += red[t + 128];
    __syncthreads();
    if (t < 64) {
        float v = red[t] + red[t + 64];
        for (int off = 32; off > 0; off >>= 1) v += __shfl_down(v, off);
        if (t == 0) demod[blockIdx.x] = rsqrtf(v + 1e-8f);
    }
}

// ---------------------------------------------------------------------------
// FOLD kernel (UNFOLDED weights — no blur): modulated+demodulated 3x3 kernel
// in MFMA B-frag layout:
//   Wt byte addr = (((b*32 + c)*8 + cb)*9 + tap)*1024 + lane*16
//   lane l holds 8 bf16: ci = c*16 + (l>>5)*8 + j, co = cb*32 + (l&31).
// tap = ky*3+kx, UNFLIPPED weight (conv-transpose math uses w directly).
// Block (b, c) of 256 threads = co. 18.9 MB output (4x less than before).
// ---------------------------------------------------------------------------
__global__ __launch_bounds__(256)
void fold_kernel(const float* __restrict__ weight,
                 const float* __restrict__ s,
                 const float* __restrict__ dm,
                 unsigned short* __restrict__ Wt) {
    int b = blockIdx.x >> 5, c = blockIdx.x & 31;
    int co = threadIdx.x;
    const float scale = 0.014731391274719739f;
    float dmv = dm[b * COUT + co] * scale;
    float m[16];
#pragma unroll
    for (int j = 0; j < 16; ++j) m[j] = s[b * CIN + c * 16 + j] * dmv;
    const float* wp = weight + ((size_t)co * CIN + c * 16) * 9;
    float wv[16][9];
#pragma unroll
    for (int j = 0; j < 16; ++j)
#pragma unroll
        for (int k = 0; k < 9; ++k) wv[j][k] = wp[j * 9 + k] * m[j];

    char* base = (char*)Wt + (((size_t)(b * 32 + c) * 8 + (co >> 5)) * 9) * 1024;
#pragma unroll
    for (int tap = 0; tap < 9; ++tap)
#pragma unroll
        for (int h = 0; h < 2; ++h) {
            unsigned int pk[4];
#pragma unroll
            for (int p = 0; p < 4; ++p) {
                unsigned short lo = f2bf(wv[h * 8 + 2 * p][tap]);
                unsigned short hi = f2bf(wv[h * 8 + 2 * p + 1][tap]);
                pk[p] = (unsigned int)lo | ((unsigned int)hi << 16);
            }
            uint4 v; v.x = pk[0]; v.y = pk[1]; v.z = pk[2]; v.w = pk[3];
            *(uint4*)(base + tap * 1024 + (((h << 5) | (co & 31)) << 4)) = v;
        }
}

// ---------------------------------------------------------------------------
// CONV kernel (UNFOLDED + fused blur).
// Block = (b, cb: 32 co, q: 8 final rows). 1024 blocks x 512 thr (8 waves).
// Computes out1 (conv-transpose, 129-grid) rows fy0-1..fy0+9 (11 rows) into
// registers: wave w owns local rows w and w+8 (w<3). Row parity: odd local
// rows are "heavy" (py=0: 2 y-taps), even are "light" (py=1: 1 y-tap).
//   out1[2Y][2X]     = sum(t0)A(R,0)+ (t2)A(R,-1) + (t6)A(R-1,0) + (t8)A(R-1,-1)
//   out1[2Y][2X+1]   = (t1)A(R,0) + (t7)A(R-1,0)
//   out1[2Y+1][2X]   = (t3)A(R,0) + (t5)A(R,-1);  out1[2Y+1][2X+1] = (t4)A(R,0)
// Edge col out1[.][128] via 3 extra MFMAs (w7, stored in its unused acc[1]).
// Epilogue: 4-row LDS ring + separable 4x4 blur in fp32, coalesced stores.
// A staged via global_load_lds dbuf: 6 input rows (4q-1..4q+4) x 66 cells x 2h
// = 792 tasks; B: 9 taps x 64 = 576; pad 1536 -> 3 issues/thread, vmcnt(3).
// ---------------------------------------------------------------------------
#define BUF_B 24576                    // 1536 tasks * 16B
#define LDS_SZ 76032                   // ring 4*32*144*4 + U 2304 (>= 2*BUF_B)

__global__ __launch_bounds__(512, 2)
void conv_kernel(const unsigned short* __restrict__ in_t,
                 const unsigned short* __restrict__ Wt,
                 const uint4* __restrict__ zeropage,
                 float* __restrict__ out) {
    __shared__ __attribute__((aligned(16))) char lds[LDS_SZ];
    int L = blockIdx.x;
    int g = (L & 7) * 128 + (L >> 3);          // XCD swizzle (bijective)
    int q = g & 15, cb = (g >> 4) & 7, b = g >> 7;
    int fy0 = q * 8;
    int Y0A = 4 * q - 1;                       // first staged input row
    int t = threadIdx.x, w = t >> 6, lane = t & 63;
    int l31 = lane & 31, hf = lane >> 5;

    const unsigned short* inb = in_t + (size_t)b * 64 * 64 * 512;

    // ---- staging pointers: 3 per thread, per-task advance ----
    const char* gp[3];
    int adv[3];
#pragma unroll
    for (int k = 0; k < 3; ++k) {
        int task = t + (k << 9);
        if (task < 792) {
            int R = task / 132;
            int rem = task - R * 132;
            int h = rem / 66, cell = rem - h * 66;
            int y = Y0A + R, x = cell - 1;
            bool ok = ((unsigned)y < 64u) && ((unsigned)x < 64u);
            gp[k] = ok ? (const char*)(inb + ((size_t)(y * 64 + x) * 512 + h * 8))
                       : (const char*)zeropage;
            adv[k] = ok ? 32 : 0;
        } else if (task < 1368) {
            int wt = task - 792;
            int tap = wt >> 6, ln = wt & 63;
            gp[k] = (const char*)Wt +
                    (((size_t)(b * 32) * 8 + cb) * 9 + tap) * 1024 + ln * 16;
            adv[k] = 73728;                    // next ci-chunk: 8cb*9tap*1024
        } else {
            gp[k] = (const char*)zeropage;
            adv[k] = 0;
        }
    }

    f32x16 acc[2][2][2];                       // [rr][px][mf]; w7: acc[1] = U
#pragma unroll
    for (int i = 0; i < 2; ++i)
#pragma unroll
        for (int j = 0; j < 2; ++j)
#pragma unroll
            for (int k = 0; k < 2; ++k) acc[i][j][k] = (f32x16)0.f;

#define STAGE(OFF)                                                              \
    {                                                                           \
        char* lb = lds + (OFF) + (w << 10);                                     \
        _Pragma("unroll")                                                       \
        for (int k = 0; k < 3; ++k) {                                           \
            __builtin_amdgcn_global_load_lds(                                   \
                (const __attribute__((address_space(1))) void*)gp[k],           \
                (__attribute__((address_space(3))) void*)(lb + (k << 13)),      \
                16, 0, 0);                                                      \
            gp[k] += adv[k];                                                    \
        }                                                                       \
    }

#define BAR()                                  \
    {                                          \
        asm volatile("" ::: "memory");         \
        __builtin_amdgcn_s_barrier();          \
        asm volatile("" ::: "memory");         \
    }

#define LDA(c) (*(const bf16x8*)(Bp + ((c) << 4)))
#define BT(tp) (*(const bf16x8*)(Bp + 12672 + ((tp) << 10) + (lane << 4)))
#define MF(a, bb, c) c = __builtin_amdgcn_mfma_f32_32x32x16_bf16(a, bb, c, 0, 0, 0)

#define COMPUTE(OFF)                                                            \
    {                                                                           \
        const char* Bp = lds + (OFF);                                           \
        if (w & 1) { /* heavy rows (py=0) */                                    \
            _Pragma("unroll")                                                   \
            for (int rr = 0; rr < 2; ++rr) {                                    \
                if (rr && w >= 3) continue;                                     \
                int R = ((w + 1) >> 1) + (rr << 2);                             \
                int c0 = (R * 2 + hf) * 66 + 1 + l31;                           \
                bf16x8 A00 = LDA(c0), A01 = LDA(c0 + 32);                       \
                bf16x8 A10 = LDA(c0 - 1), A11 = LDA(c0 + 31);                   \
                bf16x8 Ab00 = LDA(c0 - 132), Ab01 = LDA(c0 - 100);              \
                bf16x8 Ab10 = LDA(c0 - 133), Ab11 = LDA(c0 - 101);              \
                bf16x8 B0 = BT(0), B1 = BT(1), B2 = BT(2);                      \
                bf16x8 B6 = BT(6), B7 = BT(7), B8 = BT(8);                      \
                MF(A00, B0, acc[rr][0][0]); MF(A01, B0, acc[rr][0][1]);         \
                MF(A10, B2, acc[rr][0][0]); MF(A11, B2, acc[rr][0][1]);         \
                MF(A00, B1, acc[rr][1][0]); MF(A01, B1, acc[rr][1][1]);         \
                MF(Ab00, B6, acc[rr][0][0]); MF(Ab01, B6, acc[rr][0][1]);       \
                MF(Ab10, B8, acc[rr][0][0]); MF(Ab11, B8, acc[rr][0][1]);       \
                MF(Ab00, B7, acc[rr][1][0]); MF(Ab01, B7, acc[rr][1][1]);       \
            }                                                                   \
            if (w == 7) { /* edge col out1[.][128]: U_ky in acc[1] slots */     \
                int Rc = (l31 < 6) ? l31 : 5;                                   \
                bf16x8 Ae = LDA((Rc * 2 + hf) * 66 + 64);                       \
                MF(Ae, BT(2), acc[1][0][0]);                                    \
                MF(Ae, BT(5), acc[1][0][1]);                                    \
                MF(Ae, BT(8), acc[1][1][0]);                                    \
            }                                                                   \
        } else { /* light rows (py=1) */                                        \
            _Pragma("unroll")                                                   \
            for (int rr = 0; rr < 2; ++rr) {                                    \
                if (rr && w >= 3) continue;                                     \
                int R = (w >> 1) + (rr << 2);                                   \
                int c0 = (R * 2 + hf) * 66 + 1 + l31;                           \
                bf16x8 A00 = LDA(c0), A01 = LDA(c0 + 32);                       \
                bf16x8 A10 = LDA(c0 - 1), A11 = LDA(c0 + 31);                   \
                bf16x8 B3 = BT(3), B4 = BT(4), B5 = BT(5);                      \
                MF(A00, B3, acc[rr][0][0]); MF(A01, B3, acc[rr][0][1]);         \
                MF(A10, B5, acc[rr][0][0]); MF(A11, B5, acc[rr][0][1]);         \
                MF(A00, B4, acc[rr][1][0]); MF(A01, B4, acc[rr][1][1]);         \
            }                                                                   \
        }                                                                       \
    }

    STAGE(0);
#pragma unroll 1
    for (int cc = 0; cc < 32; ++cc) {
        int cur = (cc & 1) * BUF_B;
        if (cc < 31) {
            STAGE(cur ^ BUF_B);
            asm volatile("s_waitcnt vmcnt(3)" ::: "memory");
        } else {
            asm volatile("s_waitcnt vmcnt(0)" ::: "memory");
        }
        BAR();
        __builtin_amdgcn_s_setprio(1);
        COMPUTE(cur);
        __builtin_amdgcn_s_setprio(0);
        BAR();
    }
    __syncthreads();

    // =================== epilogue: fused 4x4 blur ===================
    float* Lf = (float*)lds;                   // ring [slot4][co32][144]
    float* Uf = (float*)(lds + 73728);         // U [ky3][R6][co32]

    if (w == 7) {                              // dump edge accumulators
#pragma unroll
        for (int reg = 0; reg < 4; ++reg) {
            int R = (reg & 3) + 4 * hf;
            if (R < 6) {
                Uf[(0 * 6 + R) * 32 + l31] = acc[1][0][0][reg];
                Uf[(1 * 6 + R) * 32 + l31] = acc[1][0][1][reg];
                Uf[(2 * 6 + R) * 32 + l31] = acc[1][1][0][reg];
            }
        }
    }
    // zero pad cols {0,1, 131..143} for 4 slots x 32 co (swizzle-consistent)
    for (int i = t; i < 4 * 32 * 15; i += 512) {
        int sc = i / 15, cidx = i - sc * 15;
        int col = (cidx < 2) ? cidx : (cidx + 129);
        int co = sc & 31;
        Lf[sc * 144 + (col ^ ((co & 3) << 2))] = 0.f;
    }
    __syncthreads();

    // WRITE_ROW(rr, local-row, ring slot): wave's acc row -> ring + edge col
#define WRITE_ROW(RR, R_, S)                                                    \
    {                                                                           \
        int swzw = (l31 & 3) << 2;                                              \
        float* Lr = Lf + ((S) * 32 + l31) * 144;                                \
        _Pragma("unroll")                                                       \
        for (int mf = 0; mf < 2; ++mf)                                          \
            _Pragma("unroll")                                                   \
            for (int reg = 0; reg < 16; ++reg) {                                \
                int X = (reg & 3) + ((reg >> 2) << 3) + (hf << 2) + (mf << 5);  \
                int Lc = 2 * X + 2;                                             \
                f32x2 v;                                                        \
                v.x = acc[RR][0][mf][reg];                                      \
                v.y = acc[RR][1][mf][reg];                                      \
                *(f32x2*)(Lr + (Lc ^ swzw)) = v;                                \
            }                                                                   \
        if (hf == 0) {                                                          \
            float ev;                                                           \
            if ((R_) & 1) {                                                     \
                int Ri = ((R_) + 1) >> 1;                                       \
                ev = Uf[(0 * 6 + Ri) * 32 + l31] +                              \
                     Uf[(2 * 6 + Ri - 1) * 32 + l31];                           \
            } else {                                                            \
                int Ri = (R_) >> 1;                                             \
                ev = Uf[(1 * 6 + Ri) * 32 + l31];                               \
            }                                                                   \
            Lr[130 ^ swzw] = ev;                                                \
        }                                                                       \
    }

    int co_e = t & 31, xr = t >> 5, x0 = xr * 8;
    int swzE = (co_e & 3) << 2;
    f32x4 H0[4], H1[4];

#define HCALC(S)                                                                \
    {                                                                           \
        const float* Lr = Lf + ((S) * 32 + co_e) * 144;                         \
        f32x4 q0 = *(const f32x4*)(Lr + ((x0) ^ swzE));                         \
        f32x4 q1 = *(const f32x4*)(Lr + ((x0 + 4) ^ swzE));                     \
        f32x4 q2 = *(const f32x4*)(Lr + ((x0 + 8) ^ swzE));                     \
        f32x4 q3 = *(const f32x4*)(Lr + ((x0 + 12) ^ swzE));                    \
        float e1 = q0[1], e2 = q0[2], e3 = q0[3], e4 = q1[0];                   \
        float e5 = q1[1], e6 = q1[2], e7 = q1[3], e8 = q2[0];                   \
        float e9 = q2[1], e10 = q2[2], e11 = q2[3], e12 = q3[0];                \
        f32x4 h0, h1;                                                           \
        h0[0] = 0.25f * (e1 + e4) + 0.75f * (e2 + e3);                          \
        h0[1] = 0.25f * (e2 + e5) + 0.75f * (e3 + e4);                          \
        h0[2] = 0.25f * (e3 + e6) + 0.75f * (e4 + e5);                          \
        h0[3] = 0.25f * (e4 + e7) + 0.75f * (e5 + e6);                          \
        h1[0] = 0.25f * (e5 + e8) + 0.75f * (e6 + e7);                          \
        h1[1] = 0.25f * (e6 + e9) + 0.75f * (e7 + e8);                          \
        h1[2] = 0.25f * (e7 + e10) + 0.75f * (e8 + e9);                         \
        h1[3] = 0.25f * (e8 + e11) + 0.75f * (e9 + e10);                        \
        H0[S] = h0; H1[S] = h1;                                                 \
    }

    // prefill ring rows 0..2
    if (w == 0) WRITE_ROW(0, 0, 0);
    if (w == 1) WRITE_ROW(0, 1, 1);
    if (w == 2) WRITE_ROW(0, 2, 2);
    __syncthreads();
    HCALC(0); HCALC(1); HCALC(2);

    float* outb = out + (((size_t)b * COUT + cb * 32 + co_e) * 128 + fy0) * 128 + x0;
#pragma unroll
    for (int y = 0; y < 8; ++y) {
        const int r = y + 3, s = r & 3, wr = r & 7, rrw = r >> 3;
        if (w == wr) {
            if (rrw == 0) { WRITE_ROW(0, r, s); }
            else          { WRITE_ROW(1, r, s); }
        }
        __syncthreads();
        HCALC(s);
        f32x4 o0 = 0.25f * (H0[y & 3] + H0[(y + 3) & 3]) +
                   0.75f * (H0[(y + 1) & 3] + H0[(y + 2) & 3]);
        f32x4 o1 = 0.25f * (H1[y & 3] + H1[(y + 3) & 3]) +
                   0.75f * (H1[(y + 1) & 3] + H1[(y + 2) & 3]);
        *(f32x4*)(outb + (size_t)y * 128) = o0;
        *(f32x4*)(outb + (size_t)y * 128 + 4) = o1;
        __syncthreads();
    }
#undef STAGE
#undef BAR
#undef LDA
#undef BT
#undef MF
#undef COMPUTE
#undef WRITE_ROW
#undef HCALC
}

// ---------------------------------------------------------------------------
// FALLBACK path kernels (only used if ws_size too small for MFMA pipeline)
// ---------------------------------------------------------------------------
__global__ __launch_bounds__(64)
void style_mod_kernel(const float* __restrict__ style,
                      const float* __restrict__ mod_weight,
                      const float* __restrict__ mod_bias,
                      float* __restrict__ s) {
    int idx = blockIdx.x;
    int b = idx / CIN, ci = idx % CIN;
    int lane = threadIdx.x;
    const float* mw = mod_weight + (size_t)ci * WDIM;
    const float* st = style + (size_t)b * WDIM;
    float acc = 0.f;
    for (int d = lane; d < WDIM; d += 64) acc += mw[d] * st[d];
    for (int off = 32; off > 0; off >>= 1) acc += __shfl_down(acc, off);
    if (lane == 0) s[idx] = acc * 0.04419417382415922f + mod_bias[ci];
}

__global__ __launch_bounds__(256)
void fused_upconv_blur_kernel(const float* __restrict__ input,
                              const float* __restrict__ weight,
                              const float* __restrict__ s,
                              const float* __restrict__ demod,
                              float* __restrict__ out) {
    const int t = threadIdx.x;
    const int tY = blockIdx.x >> 2, tX = blockIdx.x & 3;
    const int cob = blockIdx.y * 4;
    const int b = blockIdx.z;
    const int Y0 = tY * 16, X0 = tX * 16;
    __shared__ __attribute__((aligned(16))) float patch[19][20];
    __shared__ __attribute__((aligned(16))) float wsm[4][12];
    __shared__ __attribute__((aligned(16))) float out1[36][37];
    __shared__ __attribute__((aligned(16))) float tmpb[35][33];
    const float scale = 0.014731391274719739f;
    float dmv[4];
#pragma unroll
    for (int c = 0; c < 4; ++c) dmv[c] = demod[b * COUT + cob + c] * scale;
    float a0[4][4], a1[4][4];
#pragma unroll
    for (int c = 0; c < 4; ++c)
#pragma unroll
        for (int qq = 0; qq < 4; ++qq) { a0[c][qq] = 0.f; a1[c][qq] = 0.f; }
    const int p0 = t, p1 = t + 256;
    const int qY0 = p0 / 18, qX0 = p0 % 18;
    const int qY1s = p1 / 18, qX1 = p1 % 18;
    const bool act1 = (p1 < 324);
    const int qY1 = act1 ? qY1s : 0;
    const float* inb = input + (size_t)b * CIN * HH * WW;
    const float* sb = s + (size_t)b * CIN;
    for (int ci = 0; ci < CIN; ++ci) {
        const float* inc = inb + (size_t)ci * (HH * WW);
        for (int idx = t; idx < 361; idx += 256) {
            int rr = idx / 19, cc = idx - rr * 19;
            int gr = Y0 - 2 + rr, gc = X0 - 2 + cc;
            float v = 0.f;
            if ((unsigned)gr < 64u && (unsigned)gc < 64u) v = inc[gr * 64 + gc];
            patch[rr][cc] = v;
        }
        if (t < 36) {
            int c = t / 9, k = t - c * 9;
            wsm[c][k] = weight[((size_t)(cob + c) * CIN + ci) * 9 + k] * sb[ci] * dmv[c];
        }
        __syncthreads();
        const float i00a = patch[qY0][qX0], i01a = patch[qY0][qX0 + 1];
        const float i10a = patch[qY0 + 1][qX0], i11a = patch[qY0 + 1][qX0 + 1];
        float i00b = 0.f, i01b = 0.f, i10b = 0.f, i11b = 0.f;
        if (act1) {
            i00b = patch[qY1][qX1]; i01b = patch[qY1][qX1 + 1];
            i10b = patch[qY1 + 1][qX1]; i11b = patch[qY1 + 1][qX1 + 1];
        }
#pragma unroll
        for (int c = 0; c < 4; ++c) {
            const float4 wA = *(const float4*)&wsm[c][0];
            const float4 wB = *(const float4*)&wsm[c][4];
            const float w8v = wsm[c][8];
            a0[c][0] += i11a * wA.x + i10a * wA.z + i01a * wB.z + i00a * w8v;
            a0[c][1] += i11a * wA.y + i01a * wB.w;
            a0[c][2] += i11a * wA.w + i10a * wB.y;
            a0[c][3] += i11a * wB.x;
            if (act1) {
                a1[c][0] += i11b * wA.x + i10b * wA.z + i01b * wB.z + i00b * w8v;
                a1[c][1] += i11b * wA.y + i01b * wB.w;
                a1[c][2] += i11b * wA.w + i10b * wB.y;
                a1[c][3] += i11b * wB.x;
            }
        }
        __syncthreads();
    }
    const size_t out_base = ((size_t)b * COUT + cob) * 128 * 128;
    for (int c = 0; c < 4; ++c) {
        __syncthreads();
        out1[2 * qY0][2 * qX0] = a0[c][0];
        out1[2 * qY0][2 * qX0 + 1] = a0[c][1];
        out1[2 * qY0 + 1][2 * qX0] = a0[c][2];
        out1[2 * qY0 + 1][2 * qX0 + 1] = a0[c][3];
        if (act1) {
            out1[2 * qY1][2 * qX1] = a1[c][0];
            out1[2 * qY1][2 * qX1 + 1] = a1[c][1];
            out1[2 * qY1 + 1][2 * qX1] = a1[c][2];
            out1[2 * qY1 + 1][2 * qX1 + 1] = a1[c][3];
        }
        __syncthreads();
        for (int idx = t; idx < 35 * 32; idx += 256) {
            int rr = idx >> 5, x = idx & 31;
            tmpb[rr][x] = 0.25f * (out1[rr + 1][x + 1] + out1[rr + 1][x + 4])
                        + 0.75f * (out1[rr + 1][x + 2] + out1[rr + 1][x + 3]);
        }
        __syncthreads();
        float* outc = out + out_base + (size_t)c * 128 * 128;
        for (int idx = t; idx < 1024; idx += 256) {
            int oy = idx >> 5, x = idx & 31;
            float v = 0.25f * (tmpb[oy][x] + tmpb[oy + 3][x])
                    + 0.75f * (tmpb[oy + 1][x] + tmpb[oy + 2][x]);
            outc[(size_t)(2 * Y0 + oy) * 128 + (2 * X0 + x)] = v;
        }
    }
}

// ---------------------------------------------------------------------------
extern "C" void kernel_launch(void* const* d_in, const int* in_sizes, int n_in,
                              void* d_out, int out_size, void* d_ws, size_t ws_size,
                              hipStream_t stream) {
    const float* input      = (const float*)d_in[0];
    const float* style      = (const float*)d_in[1];
    const float* weight     = (const float*)d_in[2];
    const float* mod_weight = (const float*)d_in[3];
    const float* mod_bias   = (const float*)d_in[4];
    float* out = (float*)d_out;

    // ws layout: s(16KB) | dm(8KB) | zeropage(1KB)+pad | in_t bf16 | Wt bf16
    const size_t OFF_S = 0, OFF_DM = 16384, OFF_ZP = 24576, OFF_INT = 32768;
    const size_t OFF_W4 = OFF_INT + (size_t)BATCH * 64 * 64 * CIN * 2;      // 33587200
    const size_t WS_NEEDED = OFF_W4 + (size_t)BATCH * 4 * 9 * COUT * CIN * 2; // 109084672

    float* s_buf  = (float*)((char*)d_ws + OFF_S);
    float* dm_buf = (float*)((char*)d_ws + OFF_DM);
    uint4* zp     = (uint4*)((char*)d_ws + OFF_ZP);

    if (ws_size >= WS_NEEDED) {
        unsigned short* in_t = (unsigned short*)((char*)d_ws + OFF_INT);
        unsigned short* Wt   = (unsigned short*)((char*)d_ws + OFF_W4);
        prep_kernel<<<1536, 256, 0, stream>>>(input, style, mod_weight, mod_bias,
                                              in_t, s_buf, zp);
        demod_kernel<<<BATCH * COUT, 256, 0, stream>>>(weight, s_buf, dm_buf);
        fold_kernel<<<BATCH * 32, 256, 0, stream>>>(weight, s_buf, dm_buf, Wt);
        conv_kernel<<<1024, 512, 0, stream>>>(in_t, Wt, zp, out);
    } else {
        style_mod_kernel<<<BATCH * CIN, 64, 0, stream>>>(style, mod_weight, mod_bias, s_buf);
        demod_kernel<<<BATCH * COUT, 256, 0, stream>>>(weight, s_buf, dm_buf);
        fused_upconv_blur_kernel<<<dim3(16, COUT / 4, BATCH), 256, 0, stream>>>(
            input, weight, s_buf, dm_buf, out);
    }
}